// Round 10
// baseline (208.592 us; speedup 1.0000x reference)
//
#include <hip/hip_runtime.h>
#include <hip/hip_bf16.h>
#include <stdint.h>

typedef unsigned short u16;
typedef __attribute__((ext_vector_type(8))) __bf16 bf16x8;
typedef __attribute__((ext_vector_type(4))) float f32x4;

#define BN_EPS 1e-5f
#define MROWS 65536
#define INV_M (1.0f / 65536.0f)
#define NREP 16  // stat-buffer replication for atomic decontention

__device__ __forceinline__ u16 f2bf(float f) {
  unsigned u = __builtin_bit_cast(unsigned, f);
  unsigned r = (u + 0x7FFFu + ((u >> 16) & 1u)) >> 16;
  return (u16)r;
}
__device__ __forceinline__ float bf2f(u16 h) {
  return __builtin_bit_cast(float, (unsigned)h << 16);
}

// ------------- layer-0 stats + fp32->bf16 cast: x [65536,256] -------------
__global__ __launch_bounds__(256)
void stats_cast_k(const float* __restrict__ x, u16* __restrict__ xbf,
                  float* __restrict__ srep /* [NREP][512]: sum|sq */) {
  const int t = threadIdx.x;
  const int tc = t & 63, tr = t >> 6;
  const int rb = blockIdx.x * 32 + tr * 8;
  float4 v[8];
#pragma unroll
  for (int i = 0; i < 8; ++i)
    v[i] = *(const float4*)(x + (size_t)(rb + i) * 256 + tc * 4);
  float s0 = 0, s1 = 0, s2 = 0, s3 = 0, q0 = 0, q1 = 0, q2 = 0, q3 = 0;
#pragma unroll
  for (int i = 0; i < 8; ++i) {
    ushort4 ov;
    ov.x = f2bf(v[i].x); ov.y = f2bf(v[i].y);
    ov.z = f2bf(v[i].z); ov.w = f2bf(v[i].w);
    *(ushort4*)(xbf + (size_t)(rb + i) * 256 + tc * 4) = ov;
    s0 += v[i].x; q0 += v[i].x * v[i].x;
    s1 += v[i].y; q1 += v[i].y * v[i].y;
    s2 += v[i].z; q2 += v[i].z * v[i].z;
    s3 += v[i].w; q3 += v[i].w * v[i].w;
  }
  __shared__ float red[4][256];
  red[tr][tc * 4 + 0] = s0; red[tr][tc * 4 + 1] = s1;
  red[tr][tc * 4 + 2] = s2; red[tr][tc * 4 + 3] = s3;
  __syncthreads();
  float* dst = srep + (blockIdx.x & (NREP - 1)) * 512;
  if (tr == 0) {
#pragma unroll
    for (int i = 0; i < 4; ++i) {
      int c = tc * 4 + i;
      atomicAdd(&dst[c], red[0][c] + red[1][c] + red[2][c] + red[3][c]);
    }
  }
  __syncthreads();
  red[tr][tc * 4 + 0] = q0; red[tr][tc * 4 + 1] = q1;
  red[tr][tc * 4 + 2] = q2; red[tr][tc * 4 + 3] = q3;
  __syncthreads();
  if (tr == 0) {
#pragma unroll
    for (int i = 0; i < 4; ++i) {
      int c = tc * 4 + i;
      atomicAdd(&dst[256 + c], red[0][c] + red[1][c] + red[2][c] + red[3][c]);
    }
  }
}

// ------------- fold BN into weights: one WAVE per output row, float4 loads -------------
__global__ __launch_bounds__(256)
void prep_w_k(const float* __restrict__ W, const float* __restrict__ g,
              const float* __restrict__ b, const float* __restrict__ c,
              const float* __restrict__ ssum, const float* __restrict__ ssq,
              int rep_stride, int nrep,
              u16* __restrict__ Wp, float* __restrict__ cp, int din, int dout) {
  const int gw = (blockIdx.x * 256 + threadIdx.x) >> 6;  // global wave = row
  const int l = threadIdx.x & 63;
  if (gw >= dout) return;
  const int o = gw;
  float acc = 0.f;
  for (int d0 = l * 4; d0 < din; d0 += 256) {
    float sm[4] = {}, sq[4] = {};
    for (int r = 0; r < nrep; ++r) {
      float4 a = *(const float4*)(ssum + (size_t)r * rep_stride + d0);
      float4 z = *(const float4*)(ssq + (size_t)r * rep_stride + d0);
      sm[0] += a.x; sm[1] += a.y; sm[2] += a.z; sm[3] += a.w;
      sq[0] += z.x; sq[1] += z.y; sq[2] += z.z; sq[3] += z.w;
    }
    float4 wv = *(const float4*)(W + (size_t)o * din + d0);
    float4 gv = *(const float4*)(g + d0);
    float4 bv = *(const float4*)(b + d0);
    float w4[4] = {wv.x, wv.y, wv.z, wv.w};
    float g4[4] = {gv.x, gv.y, gv.z, gv.w};
    float b4[4] = {bv.x, bv.y, bv.z, bv.w};
    ushort4 ov;
    u16 o4[4];
#pragma unroll
    for (int i = 0; i < 4; ++i) {
      float mean = sm[i] * INV_M;
      float var = sq[i] * INV_M - mean * mean;
      float alpha = g4[i] * rsqrtf(var + BN_EPS);
      float beta = b4[i] - mean * alpha;
      o4[i] = f2bf(w4[i] * alpha);
      acc += w4[i] * beta;
    }
    ov.x = o4[0]; ov.y = o4[1]; ov.z = o4[2]; ov.w = o4[3];
    *(ushort4*)(Wp + (size_t)o * din + d0) = ov;
  }
#pragma unroll
  for (int off = 32; off > 0; off >>= 1) acc += __shfl_xor(acc, off, 64);
  if (l == 0) cp[o] = c[o] + acc;
}

// ------------- GEMM: Y = act(A @ B^T + c'), 256x256 tile, BK=32, ring-4 LDS -------------
// r10: r8 specialized structure MINUS all intra-tile fences. One barrier +
// counted vmcnt per K-tile; no setprio, no mid barrier. Rationale: r8's
// 2359 cyc/K-tile == LDS-read (1152) + MFMA (1242) SERIALIZED; the setprio
// intrinsics (side-effecting -> scheduler fences) and mid barrier prevented
// the compiler from interleaving ds_read bursts with MFMA clusters. Hazard
// audit: all slot-reuse orderings are carried by the BOUNDARY barrier alone
// (stage targets slot (T+3)&3 == (T-1)&3, whose last readers finished before
// the T-1 boundary barrier); mid-tile fences do no correctness work.
#define GLDS16(gp, lp) __builtin_amdgcn_global_load_lds( \
    (__attribute__((address_space(1))) void*)(void*)(gp), \
    (__attribute__((address_space(3))) void*)(lp), 16, 0, 0)

template <int KDIM, int NDIM, bool RELU, bool DOMAX>
__device__ __forceinline__
void gemm_body(const u16* __restrict__ A, const u16* __restrict__ B,
               const float* __restrict__ cp, u16* __restrict__ Y,
               float* __restrict__ osum, float* __restrict__ osq,
               unsigned* __restrict__ maxbuf) {
  constexpr int NK = KDIM >> 5;  // K-tiles (8 or 16)
  // ring4: A slots [4][8192] u16, then B slots [4][8192] u16  => 128 KiB
  __shared__ __align__(16) u16 lds[8 * 8192];
  const int t = threadIdx.x;
  const int w = t >> 6, l = t & 63;
  const int lr = l & 15, lk = l >> 4;
  const int wm = w >> 2, wn = w & 3;

  // XCD-aware bijective swizzle (gridDim.x % 8 == 0 for all launches here)
  const int cpx = (int)gridDim.x >> 3;
  int bid = (int)blockIdx.x;
  bid = (bid & 7) * cpx + (bid >> 3);
  constexpr int TILES_N = NDIM >> 8;
  const int tm0 = (bid / TILES_N) << 8;
  const int tn0 = (bid % TILES_N) << 8;

  // staging: tile = 256 rows x 32 u16 (16 KB), 1024 16B segs; thread t owns segs
  // t, t+512. Physical seg t -> row t>>2, slot t&3. Source slot = (t&3)^((t>>3)&3).
  const int srow = t >> 2;
  const int scol = (((t & 3) ^ ((t >> 3) & 3)) << 3);  // u16 units
  const u16* Ag = A + (size_t)(tm0 + srow) * KDIM + scol;
  const u16* Bg = B + (size_t)(tn0 + srow) * KDIM + scol;
  u16* const ldsA = lds;
  u16* const ldsB = lds + 4 * 8192;

#define STAGE_A(slot_, kt_) do { \
    GLDS16(Ag + (kt_) * 32, ldsA + (slot_) * 8192 + t * 8); \
    GLDS16(Ag + (size_t)128 * KDIM + (kt_) * 32, ldsA + (slot_) * 8192 + 4096 + t * 8); \
  } while (0)
#define STAGE_B(slot_, kt_) do { \
    GLDS16(Bg + (kt_) * 32, ldsB + (slot_) * 8192 + t * 8); \
    GLDS16(Bg + (size_t)128 * KDIM + (kt_) * 32, ldsB + (slot_) * 8192 + 4096 + t * 8); \
  } while (0)

  // ds_read: row (base + frag*16 + lr), swizzled k-slot: pc u16 = (lk ^ ((lr>>1)&3))*8
  const int pc = (lk ^ ((lr >> 1) & 3)) * 8;
  const int rba = wm * 128 + lr;  // A row base
  const int rbb = wn * 64 + lr;   // B row base

  f32x4 acc[8][4] = {};

  // prologue: stage tiles 0,1,2 (lead = 3)
  STAGE_A(0, 0); STAGE_B(0, 0);
  STAGE_A(1, 1); STAGE_B(1, 1);
  STAGE_A(2, 2); STAGE_B(2, 2);
  asm volatile("s_waitcnt vmcnt(8)" ::: "memory");  // tile 0 landed
  __builtin_amdgcn_s_barrier();

#pragma unroll
  for (int T = 0; T < NK; ++T) {
    const int sl = T & 3;  // compile-time after unroll
    const u16* la = ldsA + sl * 8192;
    const u16* lb = ldsB + sl * 8192;
    bf16x8 af[4], bf[4];
    // tile body: reads || stage || MFMA, freely schedulable by the compiler
#pragma unroll
    for (int n = 0; n < 4; ++n)
      bf[n] = *(const bf16x8*)(lb + (rbb + n * 16) * 32 + pc);
#pragma unroll
    for (int j = 0; j < 4; ++j)
      af[j] = *(const bf16x8*)(la + (rba + j * 16) * 32 + pc);
    if (T + 3 < NK) STAGE_A((T + 3) & 3, T + 3);
#pragma unroll
    for (int j = 0; j < 4; ++j)
#pragma unroll
      for (int n = 0; n < 4; ++n)
        acc[j][n] = __builtin_amdgcn_mfma_f32_16x16x32_bf16(af[j], bf[n], acc[j][n], 0, 0, 0);
#pragma unroll
    for (int j = 0; j < 4; ++j)
      af[j] = *(const bf16x8*)(la + (rba + 64 + j * 16) * 32 + pc);
    if (T + 3 < NK) STAGE_B((T + 3) & 3, T + 3);
#pragma unroll
    for (int j = 0; j < 4; ++j)
#pragma unroll
      for (int n = 0; n < 4; ++n)
        acc[4 + j][n] = __builtin_amdgcn_mfma_f32_16x16x32_bf16(af[j], bf[n], acc[4 + j][n], 0, 0, 0);
    // K-tile boundary: counted wait (never 0 mid-loop) + ONE barrier.
    if (T < NK - 3)       asm volatile("s_waitcnt vmcnt(8)" ::: "memory");
    else if (T == NK - 3) asm volatile("s_waitcnt vmcnt(4)" ::: "memory");
    else if (T == NK - 2) asm volatile("s_waitcnt vmcnt(0)" ::: "memory");
    __builtin_amdgcn_s_barrier();
  }
#undef STAGE_A
#undef STAGE_B

  if (!DOMAX) {
    float cs[4] = {}, cq[4] = {};
#pragma unroll
    for (int n = 0; n < 4; ++n) {
      const int gcol = tn0 + wn * 64 + n * 16 + lr;
      const float cb = cp[gcol];
#pragma unroll
      for (int m = 0; m < 8; ++m) {
        const int grow = tm0 + wm * 128 + m * 16 + lk * 4;
#pragma unroll
        for (int r = 0; r < 4; ++r) {
          float v = acc[m][n][r] + cb;
          if (RELU) v = fmaxf(v, 0.f);
          Y[(size_t)(grow + r) * NDIM + gcol] = f2bf(v);
          cs[n] += v;
          cq[n] += v * v;
        }
      }
    }
    if (RELU) {
#pragma unroll
      for (int n = 0; n < 4; ++n) {
        cs[n] += __shfl_xor(cs[n], 16, 64);
        cs[n] += __shfl_xor(cs[n], 32, 64);
        cq[n] += __shfl_xor(cq[n], 16, 64);
        cq[n] += __shfl_xor(cq[n], 32, 64);
      }
      float* sred = (float*)lds;  // [wm][256] sum | +512: [wm][256] sq
      __syncthreads();
      if (lk == 0) {
#pragma unroll
        for (int n = 0; n < 4; ++n) {
          const int c = wn * 64 + n * 16 + lr;
          sred[wm * 256 + c] = cs[n];
          sred[512 + wm * 256 + c] = cq[n];
        }
      }
      __syncthreads();
      if (t < 256) {
        atomicAdd(&osum[tn0 + t], sred[t] + sred[256 + t]);
      } else {
        const int c = t - 256;
        atomicAdd(&osq[tn0 + c], sred[512 + c] + sred[768 + c]);
      }
    }
  } else {
    // max-over-set epilogue: tile fully inside one batch (2048 % 256 == 0)
    const int batch = tm0 >> 11;
#pragma unroll
    for (int n = 0; n < 4; ++n) {
      const int gcol = tn0 + wn * 64 + n * 16 + lr;
      const float cb = cp[gcol];
      float mx = -3.0e38f;
#pragma unroll
      for (int m = 0; m < 8; ++m)
#pragma unroll
        for (int r = 0; r < 4; ++r)
          mx = fmaxf(mx, acc[m][n][r] + cb);
      mx = fmaxf(mx, __shfl_xor(mx, 16, 64));
      mx = fmaxf(mx, __shfl_xor(mx, 32, 64));
      if (lk == 0) {
        unsigned u = __builtin_bit_cast(unsigned, mx);
        u = (u & 0x80000000u) ? ~u : (u | 0x80000000u);
        atomicMax(&maxbuf[batch * NDIM + gcol], u);
      }
    }
  }
}

// distinct names per layer for clean profile attribution
__global__ __launch_bounds__(512, 2)
void gemm_l0(const u16* __restrict__ A, const u16* __restrict__ B,
             const float* __restrict__ cp, u16* __restrict__ Y,
             float* __restrict__ osum, float* __restrict__ osq) {
  gemm_body<256, 512, true, false>(A, B, cp, Y, osum, osq, nullptr);
}
__global__ __launch_bounds__(512, 2)
void gemm_l1(const u16* __restrict__ A, const u16* __restrict__ B,
             const float* __restrict__ cp, u16* __restrict__ Y,
             float* __restrict__ osum, float* __restrict__ osq) {
  gemm_body<512, 512, true, false>(A, B, cp, Y, osum, osq, nullptr);
}
__global__ __launch_bounds__(512, 2)
void gemm_l2(const u16* __restrict__ A, const u16* __restrict__ B,
             const float* __restrict__ cp, unsigned* __restrict__ maxbuf) {
  gemm_body<512, 1024, false, true>(A, B, cp, nullptr, nullptr, nullptr, maxbuf);
}

__global__ void decode_k(const unsigned* __restrict__ mb, float* __restrict__ out, int n) {
  int i = blockIdx.x * 256 + threadIdx.x;
  if (i < n) {
    unsigned u = mb[i];
    u = (u & 0x80000000u) ? (u & 0x7FFFFFFFu) : ~u;
    out[i] = __builtin_bit_cast(float, u);
  }
}

extern "C" void kernel_launch(void* const* d_in, const int* in_sizes, int n_in,
                              void* d_out, int out_size, void* d_ws, size_t ws_size,
                              hipStream_t stream) {
  const float* x0 = (const float*)d_in[0];
  const float* g0 = (const float*)d_in[1];
  const float* b0 = (const float*)d_in[2];
  const float* W0 = (const float*)d_in[3];
  const float* c0 = (const float*)d_in[4];
  const float* g1 = (const float*)d_in[5];
  const float* b1 = (const float*)d_in[6];
  const float* W1 = (const float*)d_in[7];
  const float* c1 = (const float*)d_in[8];
  const float* g2 = (const float*)d_in[9];
  const float* b2 = (const float*)d_in[10];
  const float* W2 = (const float*)d_in[11];
  const float* c2 = (const float*)d_in[12];

  char* ws = (char*)d_ws;
  size_t off = 0;
  auto alloc = [&](size_t bytes) -> char* {
    char* p = ws + off;
    off += (bytes + 255) & ~(size_t)255;
    return p;
  };
  u16* x0bf = (u16*)alloc((size_t)MROWS * 256 * 2);
  u16* y1 = (u16*)alloc((size_t)MROWS * 512 * 2);
  u16* y2 = (u16*)alloc((size_t)MROWS * 512 * 2);
  // contiguous zero-init region: s0 replicas [NREP][512] | stats1 | stats2 | maxbuf
  float* s0rep = (float*)alloc((NREP * 512 + 1024 + 1024 + 32768) * 4);
  float* s1sum = s0rep + NREP * 512;
  float* s1sq = s1sum + 512;
  float* s2sum = s1sum + 1024;
  float* s2sq = s2sum + 512;
  unsigned* maxbuf = (unsigned*)(s1sum + 2048);
  const size_t zbytes = (size_t)(NREP * 512 + 2048 + 32768) * 4;
  u16* W0p = (u16*)alloc(512 * 256 * 2);
  u16* W1p = (u16*)alloc(512 * 512 * 2);
  u16* W2p = (u16*)alloc(1024 * 512 * 2);
  float* c0p = (float*)alloc(512 * 4);
  float* c1p = (float*)alloc(512 * 4);
  float* c2p = (float*)alloc(1024 * 4);
  if (off > ws_size) return;

  hipMemsetAsync(s0rep, 0, zbytes, stream);

  // layer 0 (epilogue produces layer-1 BN stats)
  stats_cast_k<<<2048, 256, 0, stream>>>(x0, x0bf, s0rep);
  prep_w_k<<<128, 256, 0, stream>>>(W0, g0, b0, c0, s0rep, s0rep + 256, 512, NREP,
                                    W0p, c0p, 256, 512);
  gemm_l0<<<512, 512, 0, stream>>>(x0bf, W0p, c0p, y1, s1sum, s1sq);
  // layer 1 (epilogue produces layer-2 BN stats)
  prep_w_k<<<128, 256, 0, stream>>>(W1, g1, b1, c1, s1sum, s1sq, 0, 1,
                                    W1p, c1p, 512, 512);
  gemm_l1<<<512, 512, 0, stream>>>(y1, W1p, c1p, y2, s2sum, s2sq);
  // layer 2 + max reduction
  prep_w_k<<<256, 256, 0, stream>>>(W2, g2, b2, c2, s2sum, s2sq, 0, 1,
                                    W2p, c2p, 512, 1024);
  gemm_l2<<<1024, 512, 0, stream>>>(y2, W2p, c2p, maxbuf);
  decode_k<<<128, 256, 0, stream>>>(maxbuf, (float*)d_out, 32768);
}

// Round 11
// 201.194 us; speedup vs baseline: 1.0368x; 1.0368x over previous
//
#include <hip/hip_runtime.h>
#include <hip/hip_bf16.h>
#include <stdint.h>

typedef unsigned short u16;
typedef __attribute__((ext_vector_type(8))) __bf16 bf16x8;
typedef __attribute__((ext_vector_type(16))) float f32x16;

#define BN_EPS 1e-5f
#define MROWS 65536
#define INV_M (1.0f / 65536.0f)
#define NREP 16  // stat-buffer replication for atomic decontention

__device__ __forceinline__ u16 f2bf(float f) {
  unsigned u = __builtin_bit_cast(unsigned, f);
  unsigned r = (u + 0x7FFFu + ((u >> 16) & 1u)) >> 16;
  return (u16)r;
}
__device__ __forceinline__ float bf2f(u16 h) {
  return __builtin_bit_cast(float, (unsigned)h << 16);
}

// ------------- layer-0 stats + fp32->bf16 cast: x [65536,256] -------------
__global__ __launch_bounds__(256)
void stats_cast_k(const float* __restrict__ x, u16* __restrict__ xbf,
                  float* __restrict__ srep /* [NREP][512]: sum|sq */) {
  const int t = threadIdx.x;
  const int tc = t & 63, tr = t >> 6;
  const int rb = blockIdx.x * 32 + tr * 8;
  float4 v[8];
#pragma unroll
  for (int i = 0; i < 8; ++i)
    v[i] = *(const float4*)(x + (size_t)(rb + i) * 256 + tc * 4);
  float s0 = 0, s1 = 0, s2 = 0, s3 = 0, q0 = 0, q1 = 0, q2 = 0, q3 = 0;
#pragma unroll
  for (int i = 0; i < 8; ++i) {
    ushort4 ov;
    ov.x = f2bf(v[i].x); ov.y = f2bf(v[i].y);
    ov.z = f2bf(v[i].z); ov.w = f2bf(v[i].w);
    *(ushort4*)(xbf + (size_t)(rb + i) * 256 + tc * 4) = ov;
    s0 += v[i].x; q0 += v[i].x * v[i].x;
    s1 += v[i].y; q1 += v[i].y * v[i].y;
    s2 += v[i].z; q2 += v[i].z * v[i].z;
    s3 += v[i].w; q3 += v[i].w * v[i].w;
  }
  __shared__ float red[4][256];
  red[tr][tc * 4 + 0] = s0; red[tr][tc * 4 + 1] = s1;
  red[tr][tc * 4 + 2] = s2; red[tr][tc * 4 + 3] = s3;
  __syncthreads();
  float* dst = srep + (blockIdx.x & (NREP - 1)) * 512;
  if (tr == 0) {
#pragma unroll
    for (int i = 0; i < 4; ++i) {
      int c = tc * 4 + i;
      atomicAdd(&dst[c], red[0][c] + red[1][c] + red[2][c] + red[3][c]);
    }
  }
  __syncthreads();
  red[tr][tc * 4 + 0] = q0; red[tr][tc * 4 + 1] = q1;
  red[tr][tc * 4 + 2] = q2; red[tr][tc * 4 + 3] = q3;
  __syncthreads();
  if (tr == 0) {
#pragma unroll
    for (int i = 0; i < 4; ++i) {
      int c = tc * 4 + i;
      atomicAdd(&dst[256 + c], red[0][c] + red[1][c] + red[2][c] + red[3][c]);
    }
  }
}

// ------------- fold BN into weights: one WAVE per output row, float4 loads -------------
__global__ __launch_bounds__(256)
void prep_w_k(const float* __restrict__ W, const float* __restrict__ g,
              const float* __restrict__ b, const float* __restrict__ c,
              const float* __restrict__ ssum, const float* __restrict__ ssq,
              int rep_stride, int nrep,
              u16* __restrict__ Wp, float* __restrict__ cp, int din, int dout) {
  const int gw = (blockIdx.x * 256 + threadIdx.x) >> 6;  // global wave = row
  const int l = threadIdx.x & 63;
  if (gw >= dout) return;
  const int o = gw;
  float acc = 0.f;
  for (int d0 = l * 4; d0 < din; d0 += 256) {
    float sm[4] = {}, sq[4] = {};
    for (int r = 0; r < nrep; ++r) {
      float4 a = *(const float4*)(ssum + (size_t)r * rep_stride + d0);
      float4 z = *(const float4*)(ssq + (size_t)r * rep_stride + d0);
      sm[0] += a.x; sm[1] += a.y; sm[2] += a.z; sm[3] += a.w;
      sq[0] += z.x; sq[1] += z.y; sq[2] += z.z; sq[3] += z.w;
    }
    float4 wv = *(const float4*)(W + (size_t)o * din + d0);
    float4 gv = *(const float4*)(g + d0);
    float4 bv = *(const float4*)(b + d0);
    float w4[4] = {wv.x, wv.y, wv.z, wv.w};
    float g4[4] = {gv.x, gv.y, gv.z, gv.w};
    float b4[4] = {bv.x, bv.y, bv.z, bv.w};
    ushort4 ov;
    u16 o4[4];
#pragma unroll
    for (int i = 0; i < 4; ++i) {
      float mean = sm[i] * INV_M;
      float var = sq[i] * INV_M - mean * mean;
      float alpha = g4[i] * rsqrtf(var + BN_EPS);
      float beta = b4[i] - mean * alpha;
      o4[i] = f2bf(w4[i] * alpha);
      acc += w4[i] * beta;
    }
    ov.x = o4[0]; ov.y = o4[1]; ov.z = o4[2]; ov.w = o4[3];
    *(ushort4*)(Wp + (size_t)o * din + d0) = ov;
  }
#pragma unroll
  for (int off = 32; off > 0; off >>= 1) acc += __shfl_xor(acc, off, 64);
  if (l == 0) cp[o] = c[o] + acc;
}

// ------------- GEMM: Y = act(A @ B^T + c'), 256x256 tile, BK=32, ring-4 LDS -------------
// r11: r8 schedule verbatim (leading barrier + setprio + counted vmcnt(8),
// ring-4, both-sides swizzle, full unroll) with MFMA shape swapped to
// 32x32x16 (2382 vs 2075 TF pipe rate, half the MFMA instruction count;
// identical LDS bytes and staging). Operand maps: A/B lane row/col = l&31,
// k = (l>>5)*8; C/D col = l&31, row = (reg&3)+8*(reg>>2)+4*(l>>5).
#define GLDS16(gp, lp) __builtin_amdgcn_global_load_lds( \
    (__attribute__((address_space(1))) void*)(void*)(gp), \
    (__attribute__((address_space(3))) void*)(lp), 16, 0, 0)

template <int KDIM, int NDIM, bool RELU, bool DOMAX>
__device__ __forceinline__
void gemm_body(const u16* __restrict__ A, const u16* __restrict__ B,
               const float* __restrict__ cp, u16* __restrict__ Y,
               float* __restrict__ osum, float* __restrict__ osq,
               unsigned* __restrict__ maxbuf) {
  constexpr int NK = KDIM >> 5;  // K-tiles (8 or 16)
  // ring4: A slots [4][8192] u16, then B slots [4][8192] u16  => 128 KiB
  __shared__ __align__(16) u16 lds[8 * 8192];
  const int t = threadIdx.x;
  const int w = t >> 6, l = t & 63;
  const int l31 = l & 31, hi = l >> 5;
  const int wm = w >> 2, wn = w & 3;

  // XCD-aware bijective swizzle (gridDim.x % 8 == 0 for all launches here)
  const int cpx = (int)gridDim.x >> 3;
  int bid = (int)blockIdx.x;
  bid = (bid & 7) * cpx + (bid >> 3);
  constexpr int TILES_N = NDIM >> 8;
  const int tm0 = (bid / TILES_N) << 8;
  const int tn0 = (bid % TILES_N) << 8;

  // staging: tile = 256 rows x 32 u16 (16 KB), 1024 16B segs; thread t owns segs
  // t, t+512. Physical seg t -> row t>>2, slot t&3. Source slot = (t&3)^((t>>3)&3).
  const int srow = t >> 2;
  const int scol = (((t & 3) ^ ((t >> 3) & 3)) << 3);  // u16 units
  const u16* Ag = A + (size_t)(tm0 + srow) * KDIM + scol;
  const u16* Bg = B + (size_t)(tn0 + srow) * KDIM + scol;
  u16* const ldsA = lds;
  u16* const ldsB = lds + 4 * 8192;

#define STAGE_A(slot_, kt_) do { \
    GLDS16(Ag + (kt_) * 32, ldsA + (slot_) * 8192 + t * 8); \
    GLDS16(Ag + (size_t)128 * KDIM + (kt_) * 32, ldsA + (slot_) * 8192 + 4096 + t * 8); \
  } while (0)
#define STAGE_B(slot_, kt_) do { \
    GLDS16(Bg + (kt_) * 32, ldsB + (slot_) * 8192 + t * 8); \
    GLDS16(Bg + (size_t)128 * KDIM + (kt_) * 32, ldsB + (slot_) * 8192 + 4096 + t * 8); \
  } while (0)

  // ds_read for 32x32x16 frags: row = base + tile*32 + l31; k-chunk c = 2*kc + hi
  // (16B each); swizzled slot = c ^ ((row>>1)&3); u16 addr = row*32 + slot*8.
  // Bank audit: rows 0-7 cover all 8 bank-quads, 8-15 repeat -> free 2-way.
#define RD(base_, row_, kc_) \
  (*(const bf16x8*)((base_) + (row_) * 32 + ((((kc_) << 1) + hi) ^ (((row_) >> 1) & 3)) * 8))

  const int rba = wm * 128 + l31;  // A row base (wave M origin + lane row)
  const int rbb = wn * 64 + l31;   // B row base (wave N origin + lane col)

  f32x16 acc[4][2] = {};

  // prologue: stage tiles 0,1,2 (lead = 3)
  STAGE_A(0, 0); STAGE_B(0, 0);
  STAGE_A(1, 1); STAGE_B(1, 1);
  STAGE_A(2, 2); STAGE_B(2, 2);
  asm volatile("s_waitcnt vmcnt(8)" ::: "memory");  // tile 0 landed
  __builtin_amdgcn_s_barrier();

#pragma unroll
  for (int T = 0; T < NK; ++T) {
    const int sl = T & 3;  // compile-time after unroll
    const u16* la = ldsA + sl * 8192;
    const u16* lb = ldsB + sl * 8192;
    bf16x8 af[2][2], bf[2][2];
    // ---- phase 0: B frags (2nt x 2kc) + A frags mt=0,1 || stage A(T+3) ----
#pragma unroll
    for (int nt = 0; nt < 2; ++nt)
#pragma unroll
      for (int kc = 0; kc < 2; ++kc)
        bf[nt][kc] = RD(lb, rbb + nt * 32, kc);
#pragma unroll
    for (int mt = 0; mt < 2; ++mt)
#pragma unroll
      for (int kc = 0; kc < 2; ++kc)
        af[mt][kc] = RD(la, rba + mt * 32, kc);
    if (T + 3 < NK) STAGE_A((T + 3) & 3, T + 3);
    __builtin_amdgcn_s_barrier();
    __builtin_amdgcn_s_setprio(1);
#pragma unroll
    for (int kc = 0; kc < 2; ++kc)
#pragma unroll
      for (int mt = 0; mt < 2; ++mt)
#pragma unroll
        for (int nt = 0; nt < 2; ++nt)
          acc[mt][nt] = __builtin_amdgcn_mfma_f32_32x32x16_bf16(af[mt][kc], bf[nt][kc], acc[mt][nt], 0, 0, 0);
    __builtin_amdgcn_s_setprio(0);
    // ---- phase 1: A frags mt=2,3 (B reused in regs) || stage B(T+3) ----
#pragma unroll
    for (int mt = 0; mt < 2; ++mt)
#pragma unroll
      for (int kc = 0; kc < 2; ++kc)
        af[mt][kc] = RD(la, rba + 64 + mt * 32, kc);
    if (T + 3 < NK) STAGE_B((T + 3) & 3, T + 3);
    // K-tile boundary wait: counted, never 0 mid-loop (constants after unroll).
    if (T < NK - 3)       asm volatile("s_waitcnt vmcnt(8)" ::: "memory");
    else if (T == NK - 3) asm volatile("s_waitcnt vmcnt(4)" ::: "memory");
    else if (T == NK - 2) asm volatile("s_waitcnt vmcnt(0)" ::: "memory");
    __builtin_amdgcn_s_barrier();
    __builtin_amdgcn_s_setprio(1);
#pragma unroll
    for (int kc = 0; kc < 2; ++kc)
#pragma unroll
      for (int mt = 0; mt < 2; ++mt)
#pragma unroll
        for (int nt = 0; nt < 2; ++nt)
          acc[2 + mt][nt] = __builtin_amdgcn_mfma_f32_32x32x16_bf16(af[mt][kc], bf[nt][kc], acc[2 + mt][nt], 0, 0, 0);
    __builtin_amdgcn_s_setprio(0);
  }
#undef STAGE_A
#undef STAGE_B
#undef RD

  if (!DOMAX) {
    float cs[2] = {}, cq[2] = {};
#pragma unroll
    for (int nt = 0; nt < 2; ++nt) {
      const int gcol = tn0 + wn * 64 + nt * 32 + l31;
      const float cb = cp[gcol];
#pragma unroll
      for (int mt = 0; mt < 4; ++mt) {
#pragma unroll
        for (int rg = 0; rg < 16; ++rg) {
          const int grow = tm0 + wm * 128 + mt * 32 + (rg & 3) + 8 * (rg >> 2) + 4 * hi;
          float v = acc[mt][nt][rg] + cb;
          if (RELU) v = fmaxf(v, 0.f);
          Y[(size_t)grow * NDIM + gcol] = f2bf(v);
          cs[nt] += v;
          cq[nt] += v * v;
        }
      }
    }
    if (RELU) {
      // lanes l and l+32 share a column (complementary row halves)
#pragma unroll
      for (int nt = 0; nt < 2; ++nt) {
        cs[nt] += __shfl_xor(cs[nt], 32, 64);
        cq[nt] += __shfl_xor(cq[nt], 32, 64);
      }
      float* sred = (float*)lds;  // [wm][256] sum | +512: [wm][256] sq
      __syncthreads();
      if (hi == 0) {
#pragma unroll
        for (int nt = 0; nt < 2; ++nt) {
          const int c = wn * 64 + nt * 32 + l31;
          sred[wm * 256 + c] = cs[nt];
          sred[512 + wm * 256 + c] = cq[nt];
        }
      }
      __syncthreads();
      if (t < 256) {
        atomicAdd(&osum[tn0 + t], sred[t] + sred[256 + t]);
      } else {
        const int c = t - 256;
        atomicAdd(&osq[tn0 + c], sred[512 + c] + sred[768 + c]);
      }
    }
  } else {
    // max-over-set epilogue: tile fully inside one batch (2048 % 256 == 0)
    const int batch = tm0 >> 11;
#pragma unroll
    for (int nt = 0; nt < 2; ++nt) {
      const int gcol = tn0 + wn * 64 + nt * 32 + l31;
      const float cb = cp[gcol];
      float mx = -3.0e38f;
#pragma unroll
      for (int mt = 0; mt < 4; ++mt)
#pragma unroll
        for (int rg = 0; rg < 16; ++rg)
          mx = fmaxf(mx, acc[mt][nt][rg] + cb);
      mx = fmaxf(mx, __shfl_xor(mx, 32, 64));
      if (hi == 0) {
        unsigned u = __builtin_bit_cast(unsigned, mx);
        u = (u & 0x80000000u) ? ~u : (u | 0x80000000u);
        atomicMax(&maxbuf[batch * NDIM + gcol], u);
      }
    }
  }
}

// distinct names per layer for clean profile attribution
__global__ __launch_bounds__(512, 2)
void gemm_l0(const u16* __restrict__ A, const u16* __restrict__ B,
             const float* __restrict__ cp, u16* __restrict__ Y,
             float* __restrict__ osum, float* __restrict__ osq) {
  gemm_body<256, 512, true, false>(A, B, cp, Y, osum, osq, nullptr);
}
__global__ __launch_bounds__(512, 2)
void gemm_l1(const u16* __restrict__ A, const u16* __restrict__ B,
             const float* __restrict__ cp, u16* __restrict__ Y,
             float* __restrict__ osum, float* __restrict__ osq) {
  gemm_body<512, 512, true, false>(A, B, cp, Y, osum, osq, nullptr);
}
__global__ __launch_bounds__(512, 2)
void gemm_l2(const u16* __restrict__ A, const u16* __restrict__ B,
             const float* __restrict__ cp, unsigned* __restrict__ maxbuf) {
  gemm_body<512, 1024, false, true>(A, B, cp, nullptr, nullptr, nullptr, maxbuf);
}

__global__ void decode_k(const unsigned* __restrict__ mb, float* __restrict__ out, int n) {
  int i = blockIdx.x * 256 + threadIdx.x;
  if (i < n) {
    unsigned u = mb[i];
    u = (u & 0x80000000u) ? (u & 0x7FFFFFFFu) : ~u;
    out[i] = __builtin_bit_cast(float, u);
  }
}

extern "C" void kernel_launch(void* const* d_in, const int* in_sizes, int n_in,
                              void* d_out, int out_size, void* d_ws, size_t ws_size,
                              hipStream_t stream) {
  const float* x0 = (const float*)d_in[0];
  const float* g0 = (const float*)d_in[1];
  const float* b0 = (const float*)d_in[2];
  const float* W0 = (const float*)d_in[3];
  const float* c0 = (const float*)d_in[4];
  const float* g1 = (const float*)d_in[5];
  const float* b1 = (const float*)d_in[6];
  const float* W1 = (const float*)d_in[7];
  const float* c1 = (const float*)d_in[8];
  const float* g2 = (const float*)d_in[9];
  const float* b2 = (const float*)d_in[10];
  const float* W2 = (const float*)d_in[11];
  const float* c2 = (const float*)d_in[12];

  char* ws = (char*)d_ws;
  size_t off = 0;
  auto alloc = [&](size_t bytes) -> char* {
    char* p = ws + off;
    off += (bytes + 255) & ~(size_t)255;
    return p;
  };
  u16* x0bf = (u16*)alloc((size_t)MROWS * 256 * 2);
  u16* y1 = (u16*)alloc((size_t)MROWS * 512 * 2);
  u16* y2 = (u16*)alloc((size_t)MROWS * 512 * 2);
  // contiguous zero-init region: s0 replicas [NREP][512] | stats1 | stats2 | maxbuf
  float* s0rep = (float*)alloc((NREP * 512 + 1024 + 1024 + 32768) * 4);
  float* s1sum = s0rep + NREP * 512;
  float* s1sq = s1sum + 512;
  float* s2sum = s1sum + 1024;
  float* s2sq = s2sum + 512;
  unsigned* maxbuf = (unsigned*)(s1sum + 2048);
  const size_t zbytes = (size_t)(NREP * 512 + 2048 + 32768) * 4;
  u16* W0p = (u16*)alloc(512 * 256 * 2);
  u16* W1p = (u16*)alloc(512 * 512 * 2);
  u16* W2p = (u16*)alloc(1024 * 512 * 2);
  float* c0p = (float*)alloc(512 * 4);
  float* c1p = (float*)alloc(512 * 4);
  float* c2p = (float*)alloc(1024 * 4);
  if (off > ws_size) return;

  hipMemsetAsync(s0rep, 0, zbytes, stream);

  // layer 0 (epilogue produces layer-1 BN stats)
  stats_cast_k<<<2048, 256, 0, stream>>>(x0, x0bf, s0rep);
  prep_w_k<<<128, 256, 0, stream>>>(W0, g0, b0, c0, s0rep, s0rep + 256, 512, NREP,
                                    W0p, c0p, 256, 512);
  gemm_l0<<<512, 512, 0, stream>>>(x0bf, W0p, c0p, y1, s1sum, s1sq);
  // layer 1 (epilogue produces layer-2 BN stats)
  prep_w_k<<<128, 256, 0, stream>>>(W1, g1, b1, c1, s1sum, s1sq, 0, 1,
                                    W1p, c1p, 512, 512);
  gemm_l1<<<512, 512, 0, stream>>>(y1, W1p, c1p, y2, s2sum, s2sq);
  // layer 2 + max reduction
  prep_w_k<<<256, 256, 0, stream>>>(W2, g2, b2, c2, s2sum, s2sq, 0, 1,
                                    W2p, c2p, 512, 1024);
  gemm_l2<<<1024, 512, 0, stream>>>(y2, W2p, c2p, maxbuf);
  decode_k<<<128, 256, 0, stream>>>(maxbuf, (float*)d_out, 32768);
}

// Round 13
// 197.156 us; speedup vs baseline: 1.0580x; 1.0205x over previous
//
#include <hip/hip_runtime.h>
#include <hip/hip_bf16.h>
#include <stdint.h>

typedef unsigned short u16;
typedef __attribute__((ext_vector_type(8))) __bf16 bf16x8;
typedef __attribute__((ext_vector_type(4))) float f32x4;

#define BN_EPS 1e-5f
#define MROWS 65536
#define INV_M (1.0f / 65536.0f)
#define NREP 16  // stat-buffer replication for atomic decontention

__device__ __forceinline__ u16 f2bf(float f) {
  unsigned u = __builtin_bit_cast(unsigned, f);
  unsigned r = (u + 0x7FFFu + ((u >> 16) & 1u)) >> 16;
  return (u16)r;
}
__device__ __forceinline__ float bf2f(u16 h) {
  return __builtin_bit_cast(float, (unsigned)h << 16);
}

// ------------- layer-0 stats + fp32->bf16 cast: x [65536,256] -------------
__global__ __launch_bounds__(256)
void stats_cast_k(const float* __restrict__ x, u16* __restrict__ xbf,
                  float* __restrict__ srep /* [NREP][512]: sum|sq */) {
  const int t = threadIdx.x;
  const int tc = t & 63, tr = t >> 6;
  const int rb = blockIdx.x * 32 + tr * 8;
  float4 v[8];
#pragma unroll
  for (int i = 0; i < 8; ++i)
    v[i] = *(const float4*)(x + (size_t)(rb + i) * 256 + tc * 4);
  float s0 = 0, s1 = 0, s2 = 0, s3 = 0, q0 = 0, q1 = 0, q2 = 0, q3 = 0;
#pragma unroll
  for (int i = 0; i < 8; ++i) {
    ushort4 ov;
    ov.x = f2bf(v[i].x); ov.y = f2bf(v[i].y);
    ov.z = f2bf(v[i].z); ov.w = f2bf(v[i].w);
    *(ushort4*)(xbf + (size_t)(rb + i) * 256 + tc * 4) = ov;
    s0 += v[i].x; q0 += v[i].x * v[i].x;
    s1 += v[i].y; q1 += v[i].y * v[i].y;
    s2 += v[i].z; q2 += v[i].z * v[i].z;
    s3 += v[i].w; q3 += v[i].w * v[i].w;
  }
  __shared__ float red[4][256];
  red[tr][tc * 4 + 0] = s0; red[tr][tc * 4 + 1] = s1;
  red[tr][tc * 4 + 2] = s2; red[tr][tc * 4 + 3] = s3;
  __syncthreads();
  float* dst = srep + (blockIdx.x & (NREP - 1)) * 512;
  if (tr == 0) {
#pragma unroll
    for (int i = 0; i < 4; ++i) {
      int c = tc * 4 + i;
      atomicAdd(&dst[c], red[0][c] + red[1][c] + red[2][c] + red[3][c]);
    }
  }
  __syncthreads();
  red[tr][tc * 4 + 0] = q0; red[tr][tc * 4 + 1] = q1;
  red[tr][tc * 4 + 2] = q2; red[tr][tc * 4 + 3] = q3;
  __syncthreads();
  if (tr == 0) {
#pragma unroll
    for (int i = 0; i < 4; ++i) {
      int c = tc * 4 + i;
      atomicAdd(&dst[256 + c], red[0][c] + red[1][c] + red[2][c] + red[3][c]);
    }
  }
}

// ------------- fold BN into weights: one WAVE per output row, float4 loads -------------
__global__ __launch_bounds__(256)
void prep_w_k(const float* __restrict__ W, const float* __restrict__ g,
              const float* __restrict__ b, const float* __restrict__ c,
              const float* __restrict__ ssum, const float* __restrict__ ssq,
              int rep_stride, int nrep,
              u16* __restrict__ Wp, float* __restrict__ cp, int din, int dout) {
  const int gw = (blockIdx.x * 256 + threadIdx.x) >> 6;  // global wave = row
  const int l = threadIdx.x & 63;
  if (gw >= dout) return;
  const int o = gw;
  float acc = 0.f;
  for (int d0 = l * 4; d0 < din; d0 += 256) {
    float sm[4] = {}, sq[4] = {};
    for (int r = 0; r < nrep; ++r) {
      float4 a = *(const float4*)(ssum + (size_t)r * rep_stride + d0);
      float4 z = *(const float4*)(ssq + (size_t)r * rep_stride + d0);
      sm[0] += a.x; sm[1] += a.y; sm[2] += a.z; sm[3] += a.w;
      sq[0] += z.x; sq[1] += z.y; sq[2] += z.z; sq[3] += z.w;
    }
    float4 wv = *(const float4*)(W + (size_t)o * din + d0);
    float4 gv = *(const float4*)(g + d0);
    float4 bv = *(const float4*)(b + d0);
    float w4[4] = {wv.x, wv.y, wv.z, wv.w};
    float g4[4] = {gv.x, gv.y, gv.z, gv.w};
    float b4[4] = {bv.x, bv.y, bv.z, bv.w};
    ushort4 ov;
    u16 o4[4];
#pragma unroll
    for (int i = 0; i < 4; ++i) {
      float mean = sm[i] * INV_M;
      float var = sq[i] * INV_M - mean * mean;
      float alpha = g4[i] * rsqrtf(var + BN_EPS);
      float beta = b4[i] - mean * alpha;
      o4[i] = f2bf(w4[i] * alpha);
      acc += w4[i] * beta;
    }
    ov.x = o4[0]; ov.y = o4[1]; ov.z = o4[2]; ov.w = o4[3];
    *(ushort4*)(Wp + (size_t)o * din + d0) = ov;
  }
#pragma unroll
  for (int off = 32; off > 0; off >>= 1) acc += __shfl_xor(acc, off, 64);
  if (l == 0) cp[o] = c[o] + acc;
}

// ------------- GEMM: Y = act(A @ B^T + c'), 256x256 tile, BK=32, ring-4 LDS -------------
// r13 = r8 verbatim (the verified local optimum: l2 62.9us, 1092 TF, conflict 0).
// Structure: full compile-time specialization, ring-4 both matrices, lead-3
// staging, counted boundary vmcnt(8) (never 0 mid-loop), leading barrier +
// setprio around MFMA clusters, both-sides LDS swizzle slot^=(row>>1)&3.
// Schedule experiments r6/r7/r9/r10/r12 all regressed or broke vs this.
#define GLDS16(gp, lp) __builtin_amdgcn_global_load_lds( \
    (__attribute__((address_space(1))) void*)(void*)(gp), \
    (__attribute__((address_space(3))) void*)(lp), 16, 0, 0)

template <int KDIM, int NDIM, bool RELU, bool DOMAX>
__device__ __forceinline__
void gemm_body(const u16* __restrict__ A, const u16* __restrict__ B,
               const float* __restrict__ cp, u16* __restrict__ Y,
               float* __restrict__ osum, float* __restrict__ osq,
               unsigned* __restrict__ maxbuf) {
  constexpr int NK = KDIM >> 5;  // K-tiles (8 or 16)
  // ring4: A slots [4][8192] u16, then B slots [4][8192] u16  => 128 KiB
  __shared__ __align__(16) u16 lds[8 * 8192];
  const int t = threadIdx.x;
  const int w = t >> 6, l = t & 63;
  const int lr = l & 15, lk = l >> 4;
  const int wm = w >> 2, wn = w & 3;

  // XCD-aware bijective swizzle (gridDim.x % 8 == 0 for all launches here)
  const int cpx = (int)gridDim.x >> 3;
  int bid = (int)blockIdx.x;
  bid = (bid & 7) * cpx + (bid >> 3);
  constexpr int TILES_N = NDIM >> 8;
  const int tm0 = (bid / TILES_N) << 8;
  const int tn0 = (bid % TILES_N) << 8;

  // staging: tile = 256 rows x 32 u16 (16 KB), 1024 16B segs; thread t owns segs
  // t, t+512. Physical seg t -> row t>>2, slot t&3. Source slot = (t&3)^((t>>3)&3).
  const int srow = t >> 2;
  const int scol = (((t & 3) ^ ((t >> 3) & 3)) << 3);  // u16 units
  const u16* Ag = A + (size_t)(tm0 + srow) * KDIM + scol;
  const u16* Bg = B + (size_t)(tn0 + srow) * KDIM + scol;
  u16* const ldsA = lds;
  u16* const ldsB = lds + 4 * 8192;

#define STAGE_A(slot_, kt_) do { \
    GLDS16(Ag + (kt_) * 32, ldsA + (slot_) * 8192 + t * 8); \
    GLDS16(Ag + (size_t)128 * KDIM + (kt_) * 32, ldsA + (slot_) * 8192 + 4096 + t * 8); \
  } while (0)
#define STAGE_B(slot_, kt_) do { \
    GLDS16(Bg + (kt_) * 32, ldsB + (slot_) * 8192 + t * 8); \
    GLDS16(Bg + (size_t)128 * KDIM + (kt_) * 32, ldsB + (slot_) * 8192 + 4096 + t * 8); \
  } while (0)

  // ds_read: row (base + frag*16 + lr), swizzled k-slot: pc u16 = (lk ^ ((lr>>1)&3))*8
  const int pc = (lk ^ ((lr >> 1) & 3)) * 8;
  const int rba = wm * 128 + lr;  // A row base
  const int rbb = wn * 64 + lr;   // B row base

  f32x4 acc[8][4] = {};

  // prologue: stage tiles 0,1,2 (lead = 3)
  STAGE_A(0, 0); STAGE_B(0, 0);
  STAGE_A(1, 1); STAGE_B(1, 1);
  STAGE_A(2, 2); STAGE_B(2, 2);
  asm volatile("s_waitcnt vmcnt(8)" ::: "memory");  // tile 0 landed
  __builtin_amdgcn_s_barrier();

#pragma unroll
  for (int T = 0; T < NK; ++T) {
    const int sl = T & 3;  // compile-time after unroll
    const u16* la = ldsA + sl * 8192;
    const u16* lb = ldsB + sl * 8192;
    bf16x8 af[4], bf[4];
    // ---- phase 0: B frags (all 4) + A frags m=0..3 || stage A(T+3) ----
#pragma unroll
    for (int n = 0; n < 4; ++n)
      bf[n] = *(const bf16x8*)(lb + (rbb + n * 16) * 32 + pc);
#pragma unroll
    for (int j = 0; j < 4; ++j)
      af[j] = *(const bf16x8*)(la + (rba + j * 16) * 32 + pc);
    if (T + 3 < NK) STAGE_A((T + 3) & 3, T + 3);
    __builtin_amdgcn_s_barrier();
    __builtin_amdgcn_s_setprio(1);
#pragma unroll
    for (int j = 0; j < 4; ++j)
#pragma unroll
      for (int n = 0; n < 4; ++n)
        acc[j][n] = __builtin_amdgcn_mfma_f32_16x16x32_bf16(af[j], bf[n], acc[j][n], 0, 0, 0);
    __builtin_amdgcn_s_setprio(0);
    // ---- phase 1: A frags m=4..7 (B reused in regs) || stage B(T+3) ----
#pragma unroll
    for (int j = 0; j < 4; ++j)
      af[j] = *(const bf16x8*)(la + (rba + 64 + j * 16) * 32 + pc);
    if (T + 3 < NK) STAGE_B((T + 3) & 3, T + 3);
    // K-tile boundary wait: counted, never 0 mid-loop (constants after unroll).
    if (T < NK - 3)       asm volatile("s_waitcnt vmcnt(8)" ::: "memory");
    else if (T == NK - 3) asm volatile("s_waitcnt vmcnt(4)" ::: "memory");
    else if (T == NK - 2) asm volatile("s_waitcnt vmcnt(0)" ::: "memory");
    __builtin_amdgcn_s_barrier();
    __builtin_amdgcn_s_setprio(1);
#pragma unroll
    for (int j = 0; j < 4; ++j)
#pragma unroll
      for (int n = 0; n < 4; ++n)
        acc[4 + j][n] = __builtin_amdgcn_mfma_f32_16x16x32_bf16(af[j], bf[n], acc[4 + j][n], 0, 0, 0);
    __builtin_amdgcn_s_setprio(0);
  }
#undef STAGE_A
#undef STAGE_B

  if (!DOMAX) {
    float cs[4] = {}, cq[4] = {};
#pragma unroll
    for (int n = 0; n < 4; ++n) {
      const int gcol = tn0 + wn * 64 + n * 16 + lr;
      const float cb = cp[gcol];
#pragma unroll
      for (int m = 0; m < 8; ++m) {
        const int grow = tm0 + wm * 128 + m * 16 + lk * 4;
#pragma unroll
        for (int r = 0; r < 4; ++r) {
          float v = acc[m][n][r] + cb;
          if (RELU) v = fmaxf(v, 0.f);
          Y[(size_t)(grow + r) * NDIM + gcol] = f2bf(v);
          cs[n] += v;
          cq[n] += v * v;
        }
      }
    }
    if (RELU) {
#pragma unroll
      for (int n = 0; n < 4; ++n) {
        cs[n] += __shfl_xor(cs[n], 16, 64);
        cs[n] += __shfl_xor(cs[n], 32, 64);
        cq[n] += __shfl_xor(cq[n], 16, 64);
        cq[n] += __shfl_xor(cq[n], 32, 64);
      }
      float* sred = (float*)lds;  // [wm][256] sum | +512: [wm][256] sq
      __syncthreads();
      if (lk == 0) {
#pragma unroll
        for (int n = 0; n < 4; ++n) {
          const int c = wn * 64 + n * 16 + lr;
          sred[wm * 256 + c] = cs[n];
          sred[512 + wm * 256 + c] = cq[n];
        }
      }
      __syncthreads();
      if (t < 256) {
        atomicAdd(&osum[tn0 + t], sred[t] + sred[256 + t]);
      } else {
        const int c = t - 256;
        atomicAdd(&osq[tn0 + c], sred[512 + c] + sred[768 + c]);
      }
    }
  } else {
    // max-over-set epilogue: tile fully inside one batch (2048 % 256 == 0)
    const int batch = tm0 >> 11;
#pragma unroll
    for (int n = 0; n < 4; ++n) {
      const int gcol = tn0 + wn * 64 + n * 16 + lr;
      const float cb = cp[gcol];
      float mx = -3.0e38f;
#pragma unroll
      for (int m = 0; m < 8; ++m)
#pragma unroll
        for (int r = 0; r < 4; ++r)
          mx = fmaxf(mx, acc[m][n][r] + cb);
      mx = fmaxf(mx, __shfl_xor(mx, 16, 64));
      mx = fmaxf(mx, __shfl_xor(mx, 32, 64));
      if (lk == 0) {
        unsigned u = __builtin_bit_cast(unsigned, mx);
        u = (u & 0x80000000u) ? ~u : (u | 0x80000000u);
        atomicMax(&maxbuf[batch * NDIM + gcol], u);
      }
    }
  }
}

// distinct names per layer for clean profile attribution
__global__ __launch_bounds__(512, 2)
void gemm_l0(const u16* __restrict__ A, const u16* __restrict__ B,
             const float* __restrict__ cp, u16* __restrict__ Y,
             float* __restrict__ osum, float* __restrict__ osq) {
  gemm_body<256, 512, true, false>(A, B, cp, Y, osum, osq, nullptr);
}
__global__ __launch_bounds__(512, 2)
void gemm_l1(const u16* __restrict__ A, const u16* __restrict__ B,
             const float* __restrict__ cp, u16* __restrict__ Y,
             float* __restrict__ osum, float* __restrict__ osq) {
  gemm_body<512, 512, true, false>(A, B, cp, Y, osum, osq, nullptr);
}
__global__ __launch_bounds__(512, 2)
void gemm_l2(const u16* __restrict__ A, const u16* __restrict__ B,
             const float* __restrict__ cp, unsigned* __restrict__ maxbuf) {
  gemm_body<512, 1024, false, true>(A, B, cp, nullptr, nullptr, nullptr, maxbuf);
}

__global__ void decode_k(const unsigned* __restrict__ mb, float* __restrict__ out, int n) {
  int i = blockIdx.x * 256 + threadIdx.x;
  if (i < n) {
    unsigned u = mb[i];
    u = (u & 0x80000000u) ? (u & 0x7FFFFFFFu) : ~u;
    out[i] = __builtin_bit_cast(float, u);
  }
}

extern "C" void kernel_launch(void* const* d_in, const int* in_sizes, int n_in,
                              void* d_out, int out_size, void* d_ws, size_t ws_size,
                              hipStream_t stream) {
  const float* x0 = (const float*)d_in[0];
  const float* g0 = (const float*)d_in[1];
  const float* b0 = (const float*)d_in[2];
  const float* W0 = (const float*)d_in[3];
  const float* c0 = (const float*)d_in[4];
  const float* g1 = (const float*)d_in[5];
  const float* b1 = (const float*)d_in[6];
  const float* W1 = (const float*)d_in[7];
  const float* c1 = (const float*)d_in[8];
  const float* g2 = (const float*)d_in[9];
  const float* b2 = (const float*)d_in[10];
  const float* W2 = (const float*)d_in[11];
  const float* c2 = (const float*)d_in[12];

  char* ws = (char*)d_ws;
  size_t off = 0;
  auto alloc = [&](size_t bytes) -> char* {
    char* p = ws + off;
    off += (bytes + 255) & ~(size_t)255;
    return p;
  };
  u16* x0bf = (u16*)alloc((size_t)MROWS * 256 * 2);
  u16* y1 = (u16*)alloc((size_t)MROWS * 512 * 2);
  u16* y2 = (u16*)alloc((size_t)MROWS * 512 * 2);
  // contiguous zero-init region: s0 replicas [NREP][512] | stats1 | stats2 | maxbuf
  float* s0rep = (float*)alloc((NREP * 512 + 1024 + 1024 + 32768) * 4);
  float* s1sum = s0rep + NREP * 512;
  float* s1sq = s1sum + 512;
  float* s2sum = s1sum + 1024;
  float* s2sq = s2sum + 512;
  unsigned* maxbuf = (unsigned*)(s1sum + 2048);
  const size_t zbytes = (size_t)(NREP * 512 + 2048 + 32768) * 4;
  u16* W0p = (u16*)alloc(512 * 256 * 2);
  u16* W1p = (u16*)alloc(512 * 512 * 2);
  u16* W2p = (u16*)alloc(1024 * 512 * 2);
  float* c0p = (float*)alloc(512 * 4);
  float* c1p = (float*)alloc(512 * 4);
  float* c2p = (float*)alloc(1024 * 4);
  if (off > ws_size) return;

  hipMemsetAsync(s0rep, 0, zbytes, stream);

  // layer 0 (epilogue produces layer-1 BN stats)
  stats_cast_k<<<2048, 256, 0, stream>>>(x0, x0bf, s0rep);
  prep_w_k<<<128, 256, 0, stream>>>(W0, g0, b0, c0, s0rep, s0rep + 256, 512, NREP,
                                    W0p, c0p, 256, 512);
  gemm_l0<<<512, 512, 0, stream>>>(x0bf, W0p, c0p, y1, s1sum, s1sq);
  // layer 1 (epilogue produces layer-2 BN stats)
  prep_w_k<<<128, 256, 0, stream>>>(W1, g1, b1, c1, s1sum, s1sq, 0, 1,
                                    W1p, c1p, 512, 512);
  gemm_l1<<<512, 512, 0, stream>>>(y1, W1p, c1p, y2, s2sum, s2sq);
  // layer 2 + max reduction
  prep_w_k<<<256, 256, 0, stream>>>(W2, g2, b2, c2, s2sum, s2sq, 0, 1,
                                    W2p, c2p, 512, 1024);
  gemm_l2<<<1024, 512, 0, stream>>>(y2, W2p, c2p, maxbuf);
  decode_k<<<128, 256, 0, stream>>>(maxbuf, (float*)d_out, 32768);
}